// Round 4
// baseline (848.584 us; speedup 1.0000x reference)
//
#include <hip/hip_runtime.h>
#include <hip/hip_bf16.h>
#include <stdint.h>

#define B_  4096
#define IN_ 1024
#define H_  2048
#define K_  (IN_ + H_)   // 3072
#define N_  (5 * H_)     // 10240

// GEMM geometry: 256 rows x (64 cols/gate x 5 gates), BK=64, 8 waves.
// Wave = 128 rows x 80 cols (8 m-frags x 5 gate-frags) -> 80 MFMA per
// K-tile from 26 ds_read_b128 (matrix 3104 cyc vs LDS 2496 cyc per CU).
#define BM2 256
#define BJ2 64
#define BK2 64
#define NT2 48           // K_/BK2

typedef __attribute__((ext_vector_type(8))) short   short8;
typedef __attribute__((ext_vector_type(4))) float   f32x4;
typedef __attribute__((ext_vector_type(8))) unsigned short ushort8;

// ---------- helpers ----------
__device__ __forceinline__ unsigned short f2bf(float f) {
  union { float f; unsigned u; } cv; cv.f = f;
  unsigned u = cv.u;
  u += 0x7fffu + ((u >> 16) & 1u);   // round-to-nearest-even
  return (unsigned short)(u >> 16);
}

__device__ __forceinline__ void async16(const unsigned short* g, unsigned short* l) {
  __builtin_amdgcn_global_load_lds(
      (const __attribute__((address_space(1))) unsigned int*)g,
      (__attribute__((address_space(3))) unsigned int*)(void*)l,
      16, 0, 0);
}

__device__ __forceinline__ float fsig(float x) {
  return __builtin_amdgcn_rcpf(1.f + __expf(-x));   // rcp(inf)=0 -> safe
}
__device__ __forceinline__ float ftanh(float x) {
  return 1.f - 2.f * __builtin_amdgcn_rcpf(__expf(2.f * x) + 1.f);
}

// ---------- kernel 1: combined = bf16([x | h_prev])  [B_, K_] ----------
__global__ void build_combined(const float* __restrict__ x,
                               const float* __restrict__ h,
                               unsigned short* __restrict__ out) {
  const int row = blockIdx.x;
  const float4* xr = (const float4*)(x + (size_t)row * IN_);
  const float4* hr = (const float4*)(h + (size_t)row * H_);
  uint2* orow = (uint2*)(out + (size_t)row * K_);
  for (int c = threadIdx.x; c < K_ / 4; c += 256) {
    float4 v = (c < IN_ / 4) ? xr[c] : hr[c - IN_ / 4];
    uint2 p;
    p.x = (unsigned)f2bf(v.x) | ((unsigned)f2bf(v.y) << 16);
    p.y = (unsigned)f2bf(v.z) | ((unsigned)f2bf(v.w) << 16);
    orow[c] = p;
  }
}

// ---------- kernel 2: Wt[n][k] = bf16(W[k][n])  (64x64 LDS-tiled) ----------
__global__ __launch_bounds__(256) void transpose_convert(
    const float* __restrict__ W, unsigned short* __restrict__ Wt) {
  __shared__ float tile[64][65];
  const int n0 = blockIdx.x * 64;          // 160 blocks
  const int k0 = blockIdx.y * 64;          // 48 blocks
  const int t  = threadIdx.x;

  const int r0 = t >> 4;                   // 0..15
  const int c4 = t & 15;                   // float4 col index
  #pragma unroll
  for (int i = 0; i < 4; ++i) {
    const int kk = i * 16 + r0;
    const float4 v = *(const float4*)&W[(size_t)(k0 + kk) * N_ + n0 + c4 * 4];
    float* dst = &tile[kk][c4 * 4];
    dst[0] = v.x; dst[1] = v.y; dst[2] = v.z; dst[3] = v.w;
  }
  __syncthreads();

  #pragma unroll
  for (int i = 0; i < 2; ++i) {
    const int c2 = t + i * 256;
    const int nn = c2 >> 3;
    const int kc = (c2 & 7) * 8;
    ushort8 p;
    #pragma unroll
    for (int u = 0; u < 8; ++u) p[u] = f2bf(tile[kc + u][nn]);
    *(ushort8*)&Wt[(size_t)(n0 + nn) * K_ + k0 + kc] = p;
  }
}

// ---------- kernel 3: fused GEMM + xLSTM gate epilogue ----------
// Per-iter schedule (2 barriers / 80 MFMA per wave):
//   STAGE(t+1 -> buf^1): 9 async16/wave (4 A-chunks + 1 B-chunk per gate)
//   vmcnt(9): retire tile-t's 9 loads, keep tile-(t+1)'s in flight
//   barrier1: tile-t resident everywhere
//   reads ksub0 (13 b128) -> lgkm(0) -> 40 MFMA
//   reads ksub1 (13 b128) -> lgkm(0) -> barrier2 (WAR: buf readable done)
//   40 MFMA (overlaps other waves' next-iter stage/reads window)
// LDS 144KB dbuf -> 1 block/CU (8 waves, 2/SIMD).
__global__ __launch_bounds__(512, 2) void gemm_fused(
    const unsigned short* __restrict__ A,   // [B_, K_] bf16
    const unsigned short* __restrict__ Bt,  // [N_, K_] bf16
    const float* __restrict__ c_prev,       // [B_, H_]
    const float* __restrict__ bias,         // [5*H_]
    float* __restrict__ out)                // ht | ct
{
  __shared__ unsigned short As[2][BM2 * BK2];       // 2 x 32 KB
  __shared__ unsigned short Bs[2][5 * BJ2 * BK2];   // 2 x 40 KB

  const int tid  = threadIdx.x;
  const int wave = tid >> 6;        // 0..7
  const int lane = tid & 63;
  const int quad = lane >> 4;
  const int lr   = lane & 15;

  const int tile_m = blockIdx.x >> 5;     // 16 m-tiles
  const int tile_j = blockIdx.x & 31;     // 32 j-tiles
  const int m0 = tile_m * BM2;
  const int j0 = tile_j * BJ2;

  const int wm  = (wave & 1) * 128;       // row half (8 m-frags of 16)
  const int wnq = (wave >> 1) * 16;       // col quarter within the 64-col gate

  f32x4 acc[8][5];
  #pragma unroll
  for (int mi = 0; mi < 8; ++mi)
    #pragma unroll
    for (int g = 0; g < 5; ++g)
      acc[mi][g] = (f32x4){0.f, 0.f, 0.f, 0.f};

  // ---- staging: chunk = 8 rows x 128B. lane: row=lane>>3, phys 16B-slot
  // = lane&7; source fetches logical k-slot (lane&7)^(lane>>3) so the
  // swizzle is an involution shared with the read side (rule 21).
  const int lrow8 = lane >> 3;                       // 0..7
  const int sw8   = ((lane & 7) ^ lrow8) * 8;        // shorts

  // A-tile 256x64 = 32 chunks; wave stages {w, w+8, w+16, w+24}.
  const unsigned short* aS0 =
      A + (size_t)(m0 + 8 * wave + lrow8) * K_ + sw8;
  // B-tile rows r = gate*64 + jcol (jcol 0..63); 40 chunks; wave stages
  // chunk w+8i = gate i, jcols 8w..8w+7.
  const unsigned short* bS0 =
      Bt + (size_t)(j0 + 8 * wave + lrow8) * K_ + sw8;

  #define STAGE(ko_, bb) do {                                            \
    async16(aS0 + (ko_),                       &As[bb][512 * wave]);     \
    async16(aS0 + (size_t) 64 * K_ + (ko_),    &As[bb][512 * (wave + 8)]);  \
    async16(aS0 + (size_t)128 * K_ + (ko_),    &As[bb][512 * (wave + 16)]); \
    async16(aS0 + (size_t)192 * K_ + (ko_),    &As[bb][512 * (wave + 24)]); \
    async16(bS0 + (ko_),                       &Bs[bb][512 * wave]);     \
    async16(bS0 + (size_t)(1 * H_) * K_ + (ko_), &Bs[bb][512 * (wave + 8)]);  \
    async16(bS0 + (size_t)(2 * H_) * K_ + (ko_), &Bs[bb][512 * (wave + 16)]); \
    async16(bS0 + (size_t)(3 * H_) * K_ + (ko_), &Bs[bb][512 * (wave + 24)]); \
    async16(bS0 + (size_t)(4 * H_) * K_ + (ko_), &Bs[bb][512 * (wave + 32)]); \
  } while (0)

  // prologue: tile 0 into buffer 0 (9 outstanding)
  STAGE((size_t)0, 0);

  // fragment read slots (shorts): logical 16B-slot q = ksub*4+quad,
  // phys = q ^ (row&7); all frag rows have row&7 == lr&7.
  const int rs0 = ((0 + quad) ^ (lr & 7)) * 8;
  const int rs1 = ((4 + quad) ^ (lr & 7)) * 8;
  int aR[8], bR[5];
  #pragma unroll
  for (int mi = 0; mi < 8; ++mi) aR[mi] = (wm + mi * 16 + lr) * BK2;
  #pragma unroll
  for (int g = 0; g < 5; ++g)    bR[g]  = (g * 64 + wnq + lr) * BK2;

  #pragma unroll 2
  for (int t = 0; t < NT2; ++t) {
    const int cur = t & 1;

    // issue next tile into the other buffer (WAR-safe: its readers drained
    // at barrier2 of iter t-1), then counted wait + barrier for tile t.
    if (t < NT2 - 1) STAGE((size_t)(t + 1) * BK2, cur ^ 1);
    if (t == NT2 - 1) asm volatile("s_waitcnt vmcnt(0)" ::: "memory");
    else              asm volatile("s_waitcnt vmcnt(9)" ::: "memory");
    __builtin_amdgcn_s_barrier();          // tile-t resident everywhere

    // ---- ksub 0 ----
    short8 af0[8], bf0[5];
    #pragma unroll
    for (int mi = 0; mi < 8; ++mi)
      af0[mi] = *(const short8*)&As[cur][aR[mi] + rs0];
    #pragma unroll
    for (int g = 0; g < 5; ++g)
      bf0[g] = *(const short8*)&Bs[cur][bR[g] + rs0];
    asm volatile("s_waitcnt lgkmcnt(0)" ::: "memory");
    __builtin_amdgcn_sched_barrier(0);

    __builtin_amdgcn_s_setprio(1);
    #pragma unroll
    for (int mi = 0; mi < 8; ++mi)
      #pragma unroll
      for (int g = 0; g < 5; ++g)
        acc[mi][g] = __builtin_amdgcn_mfma_f32_16x16x32_bf16(
            af0[mi], bf0[g], acc[mi][g], 0, 0, 0);
    __builtin_amdgcn_s_setprio(0);
    __builtin_amdgcn_sched_barrier(0);

    // ---- ksub 1 ----
    short8 af1[8], bf1[5];
    #pragma unroll
    for (int mi = 0; mi < 8; ++mi)
      af1[mi] = *(const short8*)&As[cur][aR[mi] + rs1];
    #pragma unroll
    for (int g = 0; g < 5; ++g)
      bf1[g] = *(const short8*)&Bs[cur][bR[g] + rs1];
    asm volatile("s_waitcnt lgkmcnt(0)" ::: "memory");
    __builtin_amdgcn_sched_barrier(0);
    __builtin_amdgcn_s_barrier();          // all reads of buf[cur] done

    __builtin_amdgcn_s_setprio(1);
    #pragma unroll
    for (int mi = 0; mi < 8; ++mi)
      #pragma unroll
      for (int g = 0; g < 5; ++g)
        acc[mi][g] = __builtin_amdgcn_mfma_f32_16x16x32_bf16(
            af1[mi], bf1[g], acc[mi][g], 0, 0, 0);
    __builtin_amdgcn_s_setprio(0);
  }
  #undef STAGE

  // ---- fused epilogue: all 5 gates in-lane, fp32 throughout ----
  const int col = j0 + wnq + lr;                   // 0..H_-1
  float bb[5];
  #pragma unroll
  for (int g = 0; g < 5; ++g) bb[g] = bias[g * H_ + col];

  #pragma unroll
  for (int mi = 0; mi < 8; ++mi) {
    const int rbase = m0 + wm + mi * 16 + quad * 4;
    float cp[4];
    #pragma unroll
    for (int r = 0; r < 4; ++r)
      cp[r] = c_prev[(size_t)(rbase + r) * H_ + col];
    #pragma unroll
    for (int r = 0; r < 4; ++r) {
      const float ft = fsig(acc[mi][0][r] + bb[0]);
      const float it = fsig(acc[mi][1][r] + bb[1]);
      const float ch = ftanh(acc[mi][2][r] + bb[2]);
      const float ot = fsig(acc[mi][3][r] + bb[3]);
      const float et = fsig(acc[mi][4][r] + bb[4]);
      const float ct = ft * cp[r] + it * ch;
      const float th = ftanh(ct);
      float ht = ot * th;
      ht = et * __expf(ht) + (1.f - et) * ht;
      out[(size_t)(rbase + r) * H_ + col] = ht;
      out[(size_t)B_ * H_ + (size_t)(rbase + r) * H_ + col] = ct;
    }
  }
}

// ---------- launcher ----------
extern "C" void kernel_launch(void* const* d_in, const int* in_sizes, int n_in,
                              void* d_out, int out_size, void* d_ws, size_t ws_size,
                              hipStream_t stream) {
  const float* x = (const float*)d_in[0];
  const float* h = (const float*)d_in[1];
  const float* c = (const float*)d_in[2];
  const float* W = (const float*)d_in[3];
  const float* b = (const float*)d_in[4];
  float* out = (float*)d_out;

  char* ws = (char*)d_ws;
  unsigned short* combined = (unsigned short*)ws;                  // 24 MB
  unsigned short* Wt = (unsigned short*)(ws + (size_t)25165824);   // 60 MB

  build_combined<<<B_, 256, 0, stream>>>(x, h, combined);
  transpose_convert<<<dim3(N_ / 64, K_ / 64), 256, 0, stream>>>(W, Wt);
  gemm_fused<<<(B_ / BM2) * (H_ / BJ2), 512, 0, stream>>>(combined, Wt, c, b, out);
}